// Round 2
// baseline (380.330 us; speedup 1.0000x reference)
//
#include <hip/hip_runtime.h>
#include <hip/hip_bf16.h>
#include <cstdint>
#include <cstddef>

#define EPS 1e-8f

typedef __attribute__((ext_vector_type(8))) short short8;
typedef __attribute__((ext_vector_type(4))) float floatx4;

static constexpr int Bb = 16, Nn = 1024, Dd = 256, Kk = 256;
static constexpr int M = Bb * Nn;                      // 16384
static constexpr size_t PM = (size_t)M * 256;          // 4194304 elements per modality plane

// d_out element offsets (f32 elements — reference outputs are float32)
static constexpr size_t OUT_Z      = 0;                // z_rgb, z_sn
static constexpr size_t OUT_ASSIGN = 2 * PM;           // assign_rgb, assign_sn
static constexpr size_t OUT_SIM    = 4 * PM;           // sim_rgb, sim_sn
static constexpr size_t OUT_SEM    = 6 * PM;           // scalar

// ws byte offsets
static constexpr size_t OFF_Q0  = 0;                       // 2*M*256 f32 = 33,554,432 B
static constexpr size_t OFF_PN  = 33554432;                // 2*256*256 bf16
static constexpr size_t OFF_PNT = OFF_PN + 262144;
static constexpr size_t OFF_U   = OFF_PNT + 262144;        // 2*M f32
static constexpr size_t OFF_T   = OFF_U + 131072;          // 32 f32
static constexpr size_t OFF_SC  = OFF_T + 128;             // 2*6*16*256 f32
static constexpr size_t OFF_CS  = OFF_SC + 196608;         // 2*16*256 f32
static constexpr size_t ZERO_OFF = OFF_T;
static constexpr size_t ZERO_SZ  = 128 + 196608 + 32768;   // bytes (mult of 4)

__device__ __forceinline__ unsigned short f2bf(float f) {
    unsigned int b = __float_as_uint(f);
    b += 0x7fffu + ((b >> 16) & 1u);          // RNE
    return (unsigned short)(b >> 16);
}

// ---------------- zero scratch (graph-capture-safe memset) ----------------
__global__ __launch_bounds__(256) void zero_kernel(float* __restrict__ p, int n) {
    int i = blockIdx.x * 256 + threadIdx.x;
    if (i < n) p[i] = 0.f;
}

// ---------------- proto normalize: p_n [K][D] bf16 and p_nT [D][K] bf16 ----------------
__global__ __launch_bounds__(64) void proto_kernel(const float* __restrict__ pr,
                                                   const float* __restrict__ ps,
                                                   unsigned short* __restrict__ pn,
                                                   unsigned short* __restrict__ pnt) {
    int row = blockIdx.x & 255;
    int mod = blockIdx.x >> 8;
    const float* p = (mod ? ps : pr) + (size_t)row * 256;
    int lane = threadIdx.x;
    float4 v = ((const float4*)p)[lane];
    float ss = v.x * v.x + v.y * v.y + v.z * v.z + v.w * v.w;
    #pragma unroll
    for (int m = 1; m < 64; m <<= 1) ss += __shfl_xor(ss, m);
    float sc = 1.0f / (sqrtf(ss) + EPS);
    ushort4 u4;
    u4.x = f2bf(v.x * sc); u4.y = f2bf(v.y * sc);
    u4.z = f2bf(v.z * sc); u4.w = f2bf(v.w * sc);
    *(ushort4*)(pn + (size_t)mod * 65536 + (size_t)row * 256 + lane * 4) = u4;
    unsigned short* pt = pnt + (size_t)mod * 65536 + row;
    pt[(size_t)(lane * 4 + 0) * 256] = u4.x;
    pt[(size_t)(lane * 4 + 1) * 256] = u4.y;
    pt[(size_t)(lane * 4 + 2) * 256] = u4.z;
    pt[(size_t)(lane * 4 + 3) * 256] = u4.w;
}

// ---------------- MFMA GEMM, 64x64 tile, K=256 in two 128-halves ----------------
// MODE 0: C = normalize_rows(x) @ p_n^T ; epilogue: sim(f32) + q0=exp(20*sim)(f32) + T atomic
// MODE 1: C = assign(f32, from d_out) @ p_nT^T ; epilogue: z(f32)
template <int MODE>
__global__ __launch_bounds__(256) void gemm_kernel(const float* __restrict__ a_rgb,
                                                   const float* __restrict__ a_sn,
                                                   const unsigned short* __restrict__ bmat,
                                                   float* __restrict__ q0,
                                                   float* __restrict__ doutf,
                                                   float* __restrict__ Tg) {
    __shared__ short Al[64 * 136];
    __shared__ short Bl[64 * 136];

    int bx = blockIdx.x;          // col tile 0..3
    int by = blockIdx.y;          // row tile 0..255
    int mod = blockIdx.z;
    int t = threadIdx.x;
    int lane = t & 63, wv = t >> 6;
    int r = t >> 2, q = t & 3;

    const float* xrow;
    float scale;
    if (MODE == 0) {
        const float* x = mod ? a_sn : a_rgb;
        xrow = x + (size_t)(by * 64 + r) * 256;
        float ss = 0.f;
        const float4* xq = (const float4*)(xrow + q * 64);
        #pragma unroll
        for (int i = 0; i < 16; i++) {
            float4 v = xq[i];
            ss += v.x * v.x + v.y * v.y + v.z * v.z + v.w * v.w;
        }
        ss += __shfl_xor(ss, 1);
        ss += __shfl_xor(ss, 2);
        scale = 1.0f / (sqrtf(ss) + EPS);
    } else {
        xrow = doutf + OUT_ASSIGN + (size_t)mod * PM + (size_t)(by * 64 + r) * 256;
        scale = 1.0f;
    }

    floatx4 acc[2][2];
    #pragma unroll
    for (int i = 0; i < 2; i++)
        #pragma unroll
        for (int j = 0; j < 2; j++) acc[i][j] = (floatx4){0.f, 0.f, 0.f, 0.f};

    const unsigned short* bsrc = bmat + (size_t)mod * 65536;

    int rb = (wv >> 1) * 32, cbw = (wv & 1) * 32;
    int g = lane >> 4, ml = lane & 15;

    for (int h = 0; h < 2; h++) {
        // ---- stage A half (64 rows x 128 cols), f32 -> bf16 ----
        {
            int ch = q & 1, io = (q >> 1) * 8;
            const float4* src = (const float4*)(xrow + h * 128 + ch * 64);
            short* dst = &Al[r * 136 + ch * 64];
            #pragma unroll
            for (int i = 0; i < 8; i++) {
                float4 v = src[io + i];
                ushort4 u4;
                u4.x = f2bf(v.x * scale); u4.y = f2bf(v.y * scale);
                u4.z = f2bf(v.z * scale); u4.w = f2bf(v.w * scale);
                *(ushort4*)&dst[(io + i) * 4] = u4;
            }
        }
        // ---- stage B half (bf16 source) ----
        #pragma unroll
        for (int it = 0; it < 4; it++) {
            int e = it * 2048 + t * 8;
            int n = e >> 7, cc = e & 127;
            short8 vv = *(const short8*)(bsrc + (size_t)(bx * 64 + n) * 256 + h * 128 + cc);
            *(short8*)&Bl[n * 136 + cc] = vv;
        }
        __syncthreads();
        #pragma unroll
        for (int ks = 0; ks < 4; ks++) {
            int k0 = ks * 32 + g * 8;
            short8 af0 = *(const short8*)&Al[(rb + ml) * 136 + k0];
            short8 af1 = *(const short8*)&Al[(rb + 16 + ml) * 136 + k0];
            short8 bf0 = *(const short8*)&Bl[(cbw + ml) * 136 + k0];
            short8 bf1 = *(const short8*)&Bl[(cbw + 16 + ml) * 136 + k0];
            acc[0][0] = __builtin_amdgcn_mfma_f32_16x16x32_bf16(af0, bf0, acc[0][0], 0, 0, 0);
            acc[0][1] = __builtin_amdgcn_mfma_f32_16x16x32_bf16(af0, bf1, acc[0][1], 0, 0, 0);
            acc[1][0] = __builtin_amdgcn_mfma_f32_16x16x32_bf16(af1, bf0, acc[1][0], 0, 0, 0);
            acc[1][1] = __builtin_amdgcn_mfma_f32_16x16x32_bf16(af1, bf1, acc[1][1], 0, 0, 0);
        }
        __syncthreads();
    }

    // ---- epilogue (C/D layout: col=lane&15, row=(lane>>4)*4+reg) ----
    int g4 = g << 2;
    float tsum = 0.f;
    #pragma unroll
    for (int mt = 0; mt < 2; mt++)
        #pragma unroll
        for (int nt = 0; nt < 2; nt++)
            #pragma unroll
            for (int reg = 0; reg < 4; reg++) {
                float s = acc[mt][nt][reg];
                int mrow = by * 64 + rb + mt * 16 + g4 + reg;
                int col = bx * 64 + cbw + nt * 16 + ml;
                size_t idx = (size_t)mrow * 256 + col;
                if (MODE == 0) {
                    doutf[OUT_SIM + (size_t)mod * PM + idx] = s;
                    float e = __expf(s * 20.0f);          // exp(sim / tau), tau=0.05
                    q0[(size_t)mod * PM + idx] = e;
                    tsum += e;
                } else {
                    doutf[OUT_Z + (size_t)mod * PM + idx] = s;
                }
            }
    if (MODE == 0) {
        #pragma unroll
        for (int mk = 1; mk < 64; mk <<= 1) tsum += __shfl_xor(tsum, mk);
        if (lane == 0) atomicAdd(&Tg[mod * 16 + (by >> 4)], tsum);
    }
}

// ---------------- Sinkhorn pass: one fused sweep over q0 per iteration ----------------
// q_t[n][k] = q0[n][k] * u_t[n] * v_t[k]  (per batch b)
// pass 1..5: v-chain from Sc[1..p-1] -> Sr -> u update -> partial Sc[pass] atomics
// pass 6:    v-chain(v5) -> Sr -> final u -> write assign (f32) + colsum atomics
__global__ __launch_bounds__(256) void pass_kernel(const float* __restrict__ q0g,
                                                   float* __restrict__ u,
                                                   const float* __restrict__ Tg,
                                                   float* __restrict__ Sc,
                                                   float* __restrict__ cs,
                                                   float* __restrict__ doutf,
                                                   int pass) {
    __shared__ float vcur[256];
    __shared__ float wacc[4][256];
    int tile = blockIdx.x, b = blockIdx.y, mod = blockIdx.z;
    int t = threadIdx.x;
    {
        float v = 1.0f;
        for (int j = 1; j < pass; j++) {
            float sc = Sc[((size_t)(mod * 6 + j) * 16 + b) * 256 + t];
            v = v * (1.0f / 256.0f) / (v * sc + EPS);
        }
        vcur[t] = v;
        wacc[0][t] = 0.f; wacc[1][t] = 0.f; wacc[2][t] = 0.f; wacc[3][t] = 0.f;
    }
    __syncthreads();

    int r = t >> 2, q = t & 3;
    int row = b * 1024 + tile * 64 + r;
    const float* qrow = q0g + ((size_t)mod * M + row) * 256;
    const float4* q4 = (const float4*)(qrow + q * 64);
    const float4* v4 = (const float4*)(vcur + q * 64);
    float sr = 0.f;
    #pragma unroll
    for (int i = 0; i < 16; i++) {
        float4 qv = q4[i];
        float4 vv = v4[i];
        sr += qv.x * vv.x + qv.y * vv.y + qv.z * vv.z + qv.w * vv.w;
    }
    sr += __shfl_xor(sr, 1);
    sr += __shfl_xor(sr, 2);

    float up = (pass == 1) ? 1.0f / (Tg[mod * 16 + b] + EPS) : u[(size_t)mod * M + row];
    float un;
    if (pass <= 5) un = up * (1.0f / 1024.0f) / (up * sr + EPS);
    else           un = up / (up * sr + EPS);
    if (pass <= 5 && q == 0) u[(size_t)mod * M + row] = un;

    int wv = t >> 6;
    int rl = r & 15;
    int j0 = q & 3, j1 = (q + 1) & 3, j2 = (q + 2) & 3, j3 = (q + 3) & 3;
    if (pass <= 5) {
        #pragma unroll
        for (int c = 0; c < 16; c++) {
            int s = (c + rl) & 15;
            int cbb = q * 64 + s * 4;
            float4 qv = *(const float4*)(qrow + cbb);
            float4 vals = make_float4(qv.x * un, qv.y * un, qv.z * un, qv.w * un);
            float4 t1 = (q & 1) ? make_float4(vals.y, vals.z, vals.w, vals.x) : vals;
            float4 t2 = (q & 2) ? make_float4(t1.z, t1.w, t1.x, t1.y) : t1;
            wacc[wv][cbb + j0] += t2.x;
            wacc[wv][cbb + j1] += t2.y;
            wacc[wv][cbb + j2] += t2.z;
            wacc[wv][cbb + j3] += t2.w;
        }
    } else {
        float* aout = doutf + OUT_ASSIGN + (size_t)mod * PM;
        #pragma unroll
        for (int c = 0; c < 16; c++) {
            int s = (c + rl) & 15;
            int cbb = q * 64 + s * 4;
            float4 qv = *(const float4*)(qrow + cbb);
            float4 vv = *(const float4*)(vcur + cbb);
            float4 a = make_float4(qv.x * un * vv.x, qv.y * un * vv.y,
                                   qv.z * un * vv.z, qv.w * un * vv.w);
            *(float4*)(aout + (size_t)row * 256 + cbb) = a;
            float4 t1 = (q & 1) ? make_float4(a.y, a.z, a.w, a.x) : a;
            float4 t2 = (q & 2) ? make_float4(t1.z, t1.w, t1.x, t1.y) : t1;
            wacc[wv][cbb + j0] += t2.x;
            wacc[wv][cbb + j1] += t2.y;
            wacc[wv][cbb + j2] += t2.z;
            wacc[wv][cbb + j3] += t2.w;
        }
    }
    __syncthreads();
    {
        float ssum = wacc[0][t] + wacc[1][t] + wacc[2][t] + wacc[3][t];
        float* dst = (pass <= 5) ? &Sc[((size_t)(mod * 6 + pass) * 16 + b) * 256 + t]
                                 : &cs[((size_t)mod * 16 + b) * 256 + t];
        atomicAdd(dst, ssum);
    }
}

// ---------------- sem consistency scalar ----------------
// mean(A_rgb A_sn^T) = sum_b <colsum_rgb[b], colsum_sn[b]> / (B*N^2); both directions equal.
__global__ __launch_bounds__(256) void sem_kernel(const float* __restrict__ cs,
                                                  float* __restrict__ doutf) {
    int t = threadIdx.x;
    float s = 0.f;
    #pragma unroll
    for (int b = 0; b < 16; b++)
        s += cs[b * 256 + t] * cs[4096 + b * 256 + t];
    #pragma unroll
    for (int mk = 1; mk < 64; mk <<= 1) s += __shfl_xor(s, mk);
    __shared__ float red[4];
    if ((t & 63) == 0) red[t >> 6] = s;
    __syncthreads();
    if (t == 0) {
        float tot = red[0] + red[1] + red[2] + red[3];
        float mv = tot / 16777216.0f;           // B*N*N
        mv = fminf(fmaxf(mv, 0.f), 1.f);
        doutf[OUT_SEM] = 1.0f - mv;
    }
}

extern "C" void kernel_launch(void* const* d_in, const int* in_sizes, int n_in,
                              void* d_out, int out_size, void* d_ws, size_t ws_size,
                              hipStream_t stream) {
    const float* f_rgb = (const float*)d_in[0];
    const float* f_sn  = (const float*)d_in[1];
    const float* p_rgb = (const float*)d_in[2];
    const float* p_sn  = (const float*)d_in[3];
    char* ws = (char*)d_ws;
    float* q0            = (float*)(ws + OFF_Q0);
    unsigned short* pn   = (unsigned short*)(ws + OFF_PN);
    unsigned short* pnt  = (unsigned short*)(ws + OFF_PNT);
    float* u             = (float*)(ws + OFF_U);
    float* Tg            = (float*)(ws + OFF_T);
    float* Sc            = (float*)(ws + OFF_SC);
    float* cs            = (float*)(ws + OFF_CS);
    float* doutf         = (float*)d_out;

    int nz = (int)(ZERO_SZ / 4);
    zero_kernel<<<dim3((nz + 255) / 256), 256, 0, stream>>>((float*)(ws + ZERO_OFF), nz);
    proto_kernel<<<dim3(512), 64, 0, stream>>>(p_rgb, p_sn, pn, pnt);
    gemm_kernel<0><<<dim3(4, 256, 2), 256, 0, stream>>>(f_rgb, f_sn, pn, q0, doutf, Tg);
    for (int p = 1; p <= 6; p++)
        pass_kernel<<<dim3(16, 16, 2), 256, 0, stream>>>(q0, u, Tg, Sc, cs, doutf, p);
    gemm_kernel<1><<<dim3(4, 256, 2), 256, 0, stream>>>(nullptr, nullptr, pnt, q0, doutf, Tg);
    sem_kernel<<<1, 256, 0, stream>>>(cs, doutf);
}

// Round 3
// 295.143 us; speedup vs baseline: 1.2886x; 1.2886x over previous
//
#include <hip/hip_runtime.h>
#include <hip/hip_bf16.h>
#include <cstdint>
#include <cstddef>

#define EPS 1e-8f

typedef __attribute__((ext_vector_type(8))) short short8;
typedef __attribute__((ext_vector_type(4))) float floatx4;

static constexpr int Bb = 16, Nn = 1024, Dd = 256, Kk = 256;
static constexpr int M = Bb * Nn;                      // 16384
static constexpr size_t PM = (size_t)M * 256;          // 4194304 elements per modality plane

// d_out element offsets (f32)
static constexpr size_t OUT_Z      = 0;
static constexpr size_t OUT_ASSIGN = 2 * PM;
static constexpr size_t OUT_SIM    = 4 * PM;
static constexpr size_t OUT_SEM    = 6 * PM;

// ws byte offsets
static constexpr size_t OFF_XN  = 0;                   // xn bf16 2*PM (later aliased by abf)
static constexpr size_t OFF_QB  = 16777216;            // q0 bf16 2*PM
static constexpr size_t OFF_PN  = 33554432;            // pn bf16 2*64K
static constexpr size_t OFF_PNT = 33816576;            // pnt bf16
static constexpr size_t OFF_U   = 34078720;            // u f32 2*M
static constexpr size_t OFF_T   = 34209792;            // Tg 32 f32
static constexpr size_t OFF_SC  = 34209920;            // Sc 2*6*16*256 f32
static constexpr size_t OFF_CS  = 34406528;            // cs 2*16*256 f32
static constexpr size_t ZERO_OFF = OFF_T;
static constexpr size_t ZERO_SZ  = 128 + 196608 + 32768;

__device__ __forceinline__ unsigned short f2bf(float f) {
    unsigned int b = __float_as_uint(f);
    b += 0x7fffu + ((b >> 16) & 1u);          // RNE
    return (unsigned short)(b >> 16);
}
__device__ __forceinline__ float bf2f(unsigned short u) {
    return __uint_as_float(((unsigned int)u) << 16);
}

typedef const __attribute__((address_space(1))) unsigned int* gas_u32p;
typedef __attribute__((address_space(3))) unsigned int* las_u32p;
__device__ __forceinline__ void lds_cp16(const unsigned short* g, short* l) {
    __builtin_amdgcn_global_load_lds((gas_u32p)g, (las_u32p)l, 16, 0, 0);
}

// ---------------- zero scratch ----------------
__global__ __launch_bounds__(256) void zero_kernel(float* __restrict__ p, int n) {
    int i = blockIdx.x * 256 + threadIdx.x;
    if (i < n) p[i] = 0.f;
}

// ---------------- x row-normalize -> bf16 ----------------
__global__ __launch_bounds__(256) void prep_kernel(const float* __restrict__ fr,
                                                   const float* __restrict__ fs,
                                                   unsigned short* __restrict__ xn) {
    int mod = blockIdx.y;
    int row = blockIdx.x * 4 + (threadIdx.x >> 6);
    int lane = threadIdx.x & 63;
    const float* src = (mod ? fs : fr) + (size_t)row * 256;
    float4 v = ((const float4*)src)[lane];
    float ss = v.x * v.x + v.y * v.y + v.z * v.z + v.w * v.w;
    #pragma unroll
    for (int m = 1; m < 64; m <<= 1) ss += __shfl_xor(ss, m);
    float sc = 1.0f / (sqrtf(ss) + EPS);
    ushort4 u4;
    u4.x = f2bf(v.x * sc); u4.y = f2bf(v.y * sc);
    u4.z = f2bf(v.z * sc); u4.w = f2bf(v.w * sc);
    *(ushort4*)(xn + (size_t)mod * PM + (size_t)row * 256 + lane * 4) = u4;
}

// ---------------- proto normalize: p_n [K][D] bf16 and p_nT [D][K] bf16 ----------------
__global__ __launch_bounds__(64) void proto_kernel(const float* __restrict__ pr,
                                                   const float* __restrict__ ps,
                                                   unsigned short* __restrict__ pn,
                                                   unsigned short* __restrict__ pnt) {
    int row = blockIdx.x & 255;
    int mod = blockIdx.x >> 8;
    const float* p = (mod ? ps : pr) + (size_t)row * 256;
    int lane = threadIdx.x;
    float4 v = ((const float4*)p)[lane];
    float ss = v.x * v.x + v.y * v.y + v.z * v.z + v.w * v.w;
    #pragma unroll
    for (int m = 1; m < 64; m <<= 1) ss += __shfl_xor(ss, m);
    float sc = 1.0f / (sqrtf(ss) + EPS);
    ushort4 u4;
    u4.x = f2bf(v.x * sc); u4.y = f2bf(v.y * sc);
    u4.z = f2bf(v.z * sc); u4.w = f2bf(v.w * sc);
    *(ushort4*)(pn + (size_t)mod * 65536 + (size_t)row * 256 + lane * 4) = u4;
    unsigned short* pt = pnt + (size_t)mod * 65536 + row;
    pt[(size_t)(lane * 4 + 0) * 256] = u4.x;
    pt[(size_t)(lane * 4 + 1) * 256] = u4.y;
    pt[(size_t)(lane * 4 + 2) * 256] = u4.z;
    pt[(size_t)(lane * 4 + 3) * 256] = u4.w;
}

// ---------------- MFMA GEMM, 128x128 tile, BK=64, global_load_lds + XOR swizzle ----------
// C[m][n] = sum_k A[m][k]*B[n][k], A/B bf16 row-major with row stride 256.
// MODE 0: A=xn, B=pn -> sim f32 + q0 bf16 + Tg atomics.   MODE 1: A=abf, B=pnt -> z f32.
template <int MODE>
__global__ __launch_bounds__(256) void gemm_kernel(const unsigned short* __restrict__ Asrc,
                                                   const unsigned short* __restrict__ Bsrc,
                                                   unsigned short* __restrict__ qb,
                                                   float* __restrict__ doutf,
                                                   float* __restrict__ Tg) {
    __shared__ short Al[8192];   // 128 rows x 64 shorts (8 chunks of 16B), chunk-swizzled
    __shared__ short Bl[8192];

    int bx = blockIdx.x;          // col tile 0..1
    int by = blockIdx.y;          // row tile 0..127
    int mod = blockIdx.z;
    int t = threadIdx.x;
    int lane = t & 63, wv = t >> 6;
    int wrow = (wv >> 1) * 64, wcol = (wv & 1) * 64;
    int g = lane >> 4, ml = lane & 15;

    const unsigned short* A0 = Asrc + (size_t)mod * PM + (size_t)by * 128 * 256;
    const unsigned short* B0 = Bsrc + (size_t)mod * 65536 + (size_t)bx * 128 * 256;

    floatx4 acc[4][4];
    #pragma unroll
    for (int i = 0; i < 4; i++)
        #pragma unroll
        for (int j = 0; j < 4; j++) acc[i][j] = (floatx4){0.f, 0.f, 0.f, 0.f};

    for (int kh = 0; kh < 4; kh++) {
        // stage A & B K-halves: LDS slot (r, c) holds global chunk c^(r&7) of row r
        #pragma unroll
        for (int i = 0; i < 4; i++) {
            int sI = i * 256 + t;                 // linear 16B-slot index
            int r = sI >> 3, cs = sI & 7;
            int cg = cs ^ (r & 7);
            size_t goff = (size_t)r * 256 + kh * 64 + cg * 8;
            lds_cp16(A0 + goff, &Al[sI * 8]);
            lds_cp16(B0 + goff, &Bl[sI * 8]);
        }
        __syncthreads();
        #pragma unroll
        for (int ks = 0; ks < 2; ks++) {
            short8 af[4], bfr[4];
            int c = ks * 4 + g;
            #pragma unroll
            for (int mt = 0; mt < 4; mt++) {
                int row = wrow + mt * 16 + ml;
                af[mt] = *(const short8*)&Al[row * 64 + (c ^ (row & 7)) * 8];
            }
            #pragma unroll
            for (int nt = 0; nt < 4; nt++) {
                int row = wcol + nt * 16 + ml;
                bfr[nt] = *(const short8*)&Bl[row * 64 + (c ^ (row & 7)) * 8];
            }
            #pragma unroll
            for (int mt = 0; mt < 4; mt++)
                #pragma unroll
                for (int nt = 0; nt < 4; nt++)
                    acc[mt][nt] = __builtin_amdgcn_mfma_f32_16x16x32_bf16(af[mt], bfr[nt], acc[mt][nt], 0, 0, 0);
        }
        __syncthreads();
    }

    // epilogue: C/D layout col=lane&15, row=(lane>>4)*4+reg
    int g4 = g << 2;
    float tsum = 0.f;
    #pragma unroll
    for (int mt = 0; mt < 4; mt++)
        #pragma unroll
        for (int nt = 0; nt < 4; nt++)
            #pragma unroll
            for (int reg = 0; reg < 4; reg++) {
                float s = acc[mt][nt][reg];
                int row = by * 128 + wrow + mt * 16 + g4 + reg;
                int col = bx * 128 + wcol + nt * 16 + ml;
                size_t idx = (size_t)row * 256 + col;
                if (MODE == 0) {
                    doutf[OUT_SIM + (size_t)mod * PM + idx] = s;
                    unsigned short eb = f2bf(__expf(s * 20.0f));   // exp(sim/tau), tau=0.05
                    qb[(size_t)mod * PM + idx] = eb;
                    tsum += bf2f(eb);
                } else {
                    doutf[OUT_Z + (size_t)mod * PM + idx] = s;
                }
            }
    if (MODE == 0) {
        #pragma unroll
        for (int mk = 1; mk < 64; mk <<= 1) tsum += __shfl_xor(tsum, mk);
        if (lane == 0) atomicAdd(&Tg[mod * 16 + (by >> 3)], tsum);
    }
}

// ---------------- Sinkhorn pass over bf16 q0 ----------------
// pass 1..5: v-chain -> Sr -> u update -> partial Sc[pass] atomics
// pass 6:    v-chain(v5) -> Sr -> final u -> assign f32 (d_out) + assign bf16 (ws) + colsums
__global__ __launch_bounds__(256) void pass_kernel(const unsigned short* __restrict__ qbg,
                                                   float* __restrict__ u,
                                                   const float* __restrict__ Tg,
                                                   float* __restrict__ Sc,
                                                   float* __restrict__ cs,
                                                   float* __restrict__ doutf,
                                                   unsigned short* __restrict__ abf,
                                                   int pass) {
    __shared__ float vcur[256];
    __shared__ float wacc[4][256];
    int tile = blockIdx.x, b = blockIdx.y, mod = blockIdx.z;
    int t = threadIdx.x;
    {
        float v = 1.0f;
        for (int j = 1; j < pass; j++) {
            float sc = Sc[((size_t)(mod * 6 + j) * 16 + b) * 256 + t];
            v = v * (1.0f / 256.0f) / (v * sc + EPS);
        }
        vcur[t] = v;
        wacc[0][t] = 0.f; wacc[1][t] = 0.f; wacc[2][t] = 0.f; wacc[3][t] = 0.f;
    }
    __syncthreads();

    int r = t >> 2, q = t & 3;
    int row = b * 1024 + tile * 64 + r;
    const unsigned short* qrow = qbg + ((size_t)mod * M + row) * 256;
    const short8* q8 = (const short8*)(qrow + q * 64);
    const float4* v4 = (const float4*)(vcur + q * 64);
    float sr = 0.f;
    #pragma unroll
    for (int i = 0; i < 8; i++) {
        short8 qv = q8[i];
        float4 va = v4[2 * i], vb = v4[2 * i + 1];
        sr += bf2f((unsigned short)qv[0]) * va.x + bf2f((unsigned short)qv[1]) * va.y
            + bf2f((unsigned short)qv[2]) * va.z + bf2f((unsigned short)qv[3]) * va.w
            + bf2f((unsigned short)qv[4]) * vb.x + bf2f((unsigned short)qv[5]) * vb.y
            + bf2f((unsigned short)qv[6]) * vb.z + bf2f((unsigned short)qv[7]) * vb.w;
    }
    sr += __shfl_xor(sr, 1);
    sr += __shfl_xor(sr, 2);

    float up = (pass == 1) ? 1.0f / (Tg[mod * 16 + b] + EPS) : u[(size_t)mod * M + row];
    float un;
    if (pass <= 5) un = up * (1.0f / 1024.0f) / (up * sr + EPS);
    else           un = up / (up * sr + EPS);
    if (pass <= 5 && q == 0) u[(size_t)mod * M + row] = un;

    int wv = t >> 6;
    int rl = r & 15;
    int j0 = q & 3, j1 = (q + 1) & 3, j2 = (q + 2) & 3, j3 = (q + 3) & 3;
    if (pass <= 5) {
        #pragma unroll
        for (int c = 0; c < 16; c++) {
            int s = (c + rl) & 15;
            int cbb = q * 64 + s * 4;
            ushort4 qv = *(const ushort4*)(qrow + cbb);
            float4 vals = make_float4(bf2f(qv.x) * un, bf2f(qv.y) * un,
                                      bf2f(qv.z) * un, bf2f(qv.w) * un);
            float4 t1 = (q & 1) ? make_float4(vals.y, vals.z, vals.w, vals.x) : vals;
            float4 t2 = (q & 2) ? make_float4(t1.z, t1.w, t1.x, t1.y) : t1;
            wacc[wv][cbb + j0] += t2.x;
            wacc[wv][cbb + j1] += t2.y;
            wacc[wv][cbb + j2] += t2.z;
            wacc[wv][cbb + j3] += t2.w;
        }
    } else {
        float* aout = doutf + OUT_ASSIGN + (size_t)mod * PM;
        unsigned short* ab = abf + (size_t)mod * PM;
        #pragma unroll
        for (int c = 0; c < 16; c++) {
            int s = (c + rl) & 15;
            int cbb = q * 64 + s * 4;
            ushort4 qv = *(const ushort4*)(qrow + cbb);
            float4 vv = *(const float4*)(vcur + cbb);
            float4 a = make_float4(bf2f(qv.x) * un * vv.x, bf2f(qv.y) * un * vv.y,
                                   bf2f(qv.z) * un * vv.z, bf2f(qv.w) * un * vv.w);
            *(float4*)(aout + (size_t)row * 256 + cbb) = a;
            ushort4 o;
            o.x = f2bf(a.x); o.y = f2bf(a.y); o.z = f2bf(a.z); o.w = f2bf(a.w);
            *(ushort4*)(ab + (size_t)row * 256 + cbb) = o;
            float4 t1 = (q & 1) ? make_float4(a.y, a.z, a.w, a.x) : a;
            float4 t2 = (q & 2) ? make_float4(t1.z, t1.w, t1.x, t1.y) : t1;
            wacc[wv][cbb + j0] += t2.x;
            wacc[wv][cbb + j1] += t2.y;
            wacc[wv][cbb + j2] += t2.z;
            wacc[wv][cbb + j3] += t2.w;
        }
    }
    __syncthreads();
    {
        float ssum = wacc[0][t] + wacc[1][t] + wacc[2][t] + wacc[3][t];
        float* dst = (pass <= 5) ? &Sc[((size_t)(mod * 6 + pass) * 16 + b) * 256 + t]
                                 : &cs[((size_t)mod * 16 + b) * 256 + t];
        atomicAdd(dst, ssum);
    }
}

// ---------------- sem consistency scalar ----------------
__global__ __launch_bounds__(256) void sem_kernel(const float* __restrict__ cs,
                                                  float* __restrict__ doutf) {
    int t = threadIdx.x;
    float s = 0.f;
    #pragma unroll
    for (int b = 0; b < 16; b++)
        s += cs[b * 256 + t] * cs[4096 + b * 256 + t];
    #pragma unroll
    for (int mk = 1; mk < 64; mk <<= 1) s += __shfl_xor(s, mk);
    __shared__ float red[4];
    if ((t & 63) == 0) red[t >> 6] = s;
    __syncthreads();
    if (t == 0) {
        float tot = red[0] + red[1] + red[2] + red[3];
        float mv = tot / 16777216.0f;           // B*N*N
        mv = fminf(fmaxf(mv, 0.f), 1.f);
        doutf[OUT_SEM] = 1.0f - mv;
    }
}

extern "C" void kernel_launch(void* const* d_in, const int* in_sizes, int n_in,
                              void* d_out, int out_size, void* d_ws, size_t ws_size,
                              hipStream_t stream) {
    const float* f_rgb = (const float*)d_in[0];
    const float* f_sn  = (const float*)d_in[1];
    const float* p_rgb = (const float*)d_in[2];
    const float* p_sn  = (const float*)d_in[3];
    char* ws = (char*)d_ws;
    unsigned short* xn   = (unsigned short*)(ws + OFF_XN);
    unsigned short* abf  = (unsigned short*)(ws + OFF_XN);   // aliases xn (dead after gemm0)
    unsigned short* qb   = (unsigned short*)(ws + OFF_QB);
    unsigned short* pn   = (unsigned short*)(ws + OFF_PN);
    unsigned short* pnt  = (unsigned short*)(ws + OFF_PNT);
    float* u             = (float*)(ws + OFF_U);
    float* Tg            = (float*)(ws + OFF_T);
    float* Sc            = (float*)(ws + OFF_SC);
    float* cs            = (float*)(ws + OFF_CS);
    float* doutf         = (float*)d_out;

    int nz = (int)(ZERO_SZ / 4);
    zero_kernel<<<dim3((nz + 255) / 256), 256, 0, stream>>>((float*)(ws + ZERO_OFF), nz);
    prep_kernel<<<dim3(4096, 2), 256, 0, stream>>>(f_rgb, f_sn, xn);
    proto_kernel<<<dim3(512), 64, 0, stream>>>(p_rgb, p_sn, pn, pnt);
    gemm_kernel<0><<<dim3(2, 128, 2), 256, 0, stream>>>(xn, pn, qb, doutf, Tg);
    for (int p = 1; p <= 6; p++)
        pass_kernel<<<dim3(16, 16, 2), 256, 0, stream>>>(qb, u, Tg, Sc, cs, doutf, abf, p);
    gemm_kernel<1><<<dim3(2, 128, 2), 256, 0, stream>>>(abf, pnt, qb, doutf, Tg);
    sem_kernel<<<1, 256, 0, stream>>>(cs, doutf);
}

// Round 4
// 211.012 us; speedup vs baseline: 1.8024x; 1.3987x over previous
//
#include <hip/hip_runtime.h>
#include <hip/hip_bf16.h>
#include <cstdint>
#include <cstddef>

#define EPS 1e-8f

typedef __attribute__((ext_vector_type(8))) short short8;
typedef __attribute__((ext_vector_type(4))) float floatx4;

static constexpr int Bb = 16, Nn = 1024, Dd = 256, Kk = 256;
static constexpr int M = Bb * Nn;                      // 16384
static constexpr size_t PM = (size_t)M * 256;          // 4,194,304 elements per modality plane

// d_out element offsets (f32)
static constexpr size_t OUT_Z      = 0;
static constexpr size_t OUT_ASSIGN = 2 * PM;
static constexpr size_t OUT_SIM    = 4 * PM;
static constexpr size_t OUT_SEM    = 6 * PM;

// ws byte offsets
static constexpr size_t OFF_XN  = 0;                   // xn bf16 2*PM (aliased by abf later)
static constexpr size_t OFF_QB  = 16777216;            // q0 bf16 2*PM
static constexpr size_t OFF_PN  = 33554432;            // pn bf16 2*64K
static constexpr size_t OFF_PNT = 33816576;            // pnt bf16
static constexpr size_t OFF_U   = 34078720;            // u f32 2*M
static constexpr size_t OFF_T   = 34209792;            // Tg 32 f32
static constexpr size_t OFF_SC  = 34209920;            // Sc 2*6*16*256 f32
static constexpr size_t OFF_CS  = 34406528;            // cs 2*16*256 f32
static constexpr size_t ZERO_OFF = OFF_T;
static constexpr size_t ZERO_SZ  = 128 + 196608 + 32768;
static constexpr int    NZ_FLOATS = (int)(ZERO_SZ / 4);

__device__ __forceinline__ unsigned short f2bf(float f) {
    unsigned int b = __float_as_uint(f);
    b += 0x7fffu + ((b >> 16) & 1u);          // RNE
    return (unsigned short)(b >> 16);
}
__device__ __forceinline__ float bf2f(unsigned short u) {
    return __uint_as_float(((unsigned int)u) << 16);
}

typedef const __attribute__((address_space(1))) unsigned int* gas_u32p;
typedef __attribute__((address_space(3))) unsigned int* las_u32p;
__device__ __forceinline__ void lds_cp16(const unsigned short* g, short* l) {
    __builtin_amdgcn_global_load_lds((gas_u32p)g, (las_u32p)l, 16, 0, 0);
}

// ---------------- x row-normalize -> bf16 ----------------
__global__ __launch_bounds__(256) void prep_kernel(const float* __restrict__ fr,
                                                   const float* __restrict__ fs,
                                                   unsigned short* __restrict__ xn) {
    int mod = blockIdx.y;
    int row = blockIdx.x * 4 + (threadIdx.x >> 6);
    int lane = threadIdx.x & 63;
    const float* src = (mod ? fs : fr) + (size_t)row * 256;
    float4 v = ((const float4*)src)[lane];
    float ss = v.x * v.x + v.y * v.y + v.z * v.z + v.w * v.w;
    #pragma unroll
    for (int m = 1; m < 64; m <<= 1) ss += __shfl_xor(ss, m);
    float sc = 1.0f / (sqrtf(ss) + EPS);
    ushort4 u4;
    u4.x = f2bf(v.x * sc); u4.y = f2bf(v.y * sc);
    u4.z = f2bf(v.z * sc); u4.w = f2bf(v.w * sc);
    *(ushort4*)(xn + (size_t)mod * PM + (size_t)row * 256 + lane * 4) = u4;
}

// ---------------- proto normalize (+ fused scratch zeroing) ----------------
__global__ __launch_bounds__(64) void proto_kernel(const float* __restrict__ pr,
                                                   const float* __restrict__ ps,
                                                   unsigned short* __restrict__ pn,
                                                   unsigned short* __restrict__ pnt,
                                                   float* __restrict__ zp) {
    int gid = blockIdx.x * 64 + threadIdx.x;           // 0..32767
    for (int i = gid; i < NZ_FLOATS; i += 32768) zp[i] = 0.f;

    int row = blockIdx.x & 255;
    int mod = blockIdx.x >> 8;
    const float* p = (mod ? ps : pr) + (size_t)row * 256;
    int lane = threadIdx.x;
    float4 v = ((const float4*)p)[lane];
    float ss = v.x * v.x + v.y * v.y + v.z * v.z + v.w * v.w;
    #pragma unroll
    for (int m = 1; m < 64; m <<= 1) ss += __shfl_xor(ss, m);
    float sc = 1.0f / (sqrtf(ss) + EPS);
    ushort4 u4;
    u4.x = f2bf(v.x * sc); u4.y = f2bf(v.y * sc);
    u4.z = f2bf(v.z * sc); u4.w = f2bf(v.w * sc);
    *(ushort4*)(pn + (size_t)mod * 65536 + (size_t)row * 256 + lane * 4) = u4;
    unsigned short* pt = pnt + (size_t)mod * 65536 + row;
    pt[(size_t)(lane * 4 + 0) * 256] = u4.x;
    pt[(size_t)(lane * 4 + 1) * 256] = u4.y;
    pt[(size_t)(lane * 4 + 2) * 256] = u4.z;
    pt[(size_t)(lane * 4 + 3) * 256] = u4.w;
}

// ---------------- MFMA GEMM, 128x128 tile, BK=64, global_load_lds + XOR swizzle ----------
// C[m][n] = sum_k A[m][k]*B[n][k], A/B bf16 row-major, row stride 256.
// MODE 0: A=xn, B=pn -> sim f32 + q0 bf16 + Tg atomics.   MODE 1: A=abf, B=pnt -> z f32.
template <int MODE>
__global__ __launch_bounds__(256) void gemm_kernel(const unsigned short* __restrict__ Asrc,
                                                   const unsigned short* __restrict__ Bsrc,
                                                   unsigned short* __restrict__ qb,
                                                   float* __restrict__ doutf,
                                                   float* __restrict__ Tg) {
    __shared__ short Al[8192];   // 128 rows x 64 shorts (8 chunks of 16B), chunk-swizzled
    __shared__ short Bl[8192];

    int bx = blockIdx.x;          // col tile 0..1
    int by = blockIdx.y;          // row tile 0..127
    int mod = blockIdx.z;
    int t = threadIdx.x;
    int lane = t & 63, wv = t >> 6;
    int wrow = (wv >> 1) * 64, wcol = (wv & 1) * 64;
    int g = lane >> 4, ml = lane & 15;

    const unsigned short* A0 = Asrc + (size_t)mod * PM + (size_t)by * 128 * 256;
    const unsigned short* B0 = Bsrc + (size_t)mod * 65536 + (size_t)bx * 128 * 256;

    floatx4 acc[4][4];
    #pragma unroll
    for (int i = 0; i < 4; i++)
        #pragma unroll
        for (int j = 0; j < 4; j++) acc[i][j] = (floatx4){0.f, 0.f, 0.f, 0.f};

    for (int kh = 0; kh < 4; kh++) {
        #pragma unroll
        for (int i = 0; i < 4; i++) {
            int sI = i * 256 + t;                 // linear 16B-slot index
            int r = sI >> 3, cs = sI & 7;
            int cg = cs ^ (r & 7);
            size_t goff = (size_t)r * 256 + kh * 64 + cg * 8;
            lds_cp16(A0 + goff, &Al[sI * 8]);
            lds_cp16(B0 + goff, &Bl[sI * 8]);
        }
        __syncthreads();
        #pragma unroll
        for (int ks = 0; ks < 2; ks++) {
            short8 af[4], bfr[4];
            int c = ks * 4 + g;
            #pragma unroll
            for (int mt = 0; mt < 4; mt++) {
                int row = wrow + mt * 16 + ml;
                af[mt] = *(const short8*)&Al[row * 64 + (c ^ (row & 7)) * 8];
            }
            #pragma unroll
            for (int nt = 0; nt < 4; nt++) {
                int row = wcol + nt * 16 + ml;
                bfr[nt] = *(const short8*)&Bl[row * 64 + (c ^ (row & 7)) * 8];
            }
            #pragma unroll
            for (int mt = 0; mt < 4; mt++)
                #pragma unroll
                for (int nt = 0; nt < 4; nt++)
                    acc[mt][nt] = __builtin_amdgcn_mfma_f32_16x16x32_bf16(af[mt], bfr[nt], acc[mt][nt], 0, 0, 0);
        }
        __syncthreads();
    }

    // epilogue: C/D layout col=lane&15, row=(lane>>4)*4+reg
    int g4 = g << 2;
    float tsum = 0.f;
    #pragma unroll
    for (int mt = 0; mt < 4; mt++)
        #pragma unroll
        for (int nt = 0; nt < 4; nt++)
            #pragma unroll
            for (int reg = 0; reg < 4; reg++) {
                float s = acc[mt][nt][reg];
                int row = by * 128 + wrow + mt * 16 + g4 + reg;
                int col = bx * 128 + wcol + nt * 16 + ml;
                size_t idx = (size_t)row * 256 + col;
                if (MODE == 0) {
                    doutf[OUT_SIM + (size_t)mod * PM + idx] = s;
                    unsigned short eb = f2bf(__expf(s * 20.0f));   // exp(sim/tau), tau=0.05
                    qb[(size_t)mod * PM + idx] = eb;
                    tsum += bf2f(eb);
                } else {
                    doutf[OUT_Z + (size_t)mod * PM + idx] = s;
                }
            }
    if (MODE == 0) {
        #pragma unroll
        for (int mk = 1; mk < 64; mk <<= 1) tsum += __shfl_xor(tsum, mk);
        if (lane == 0) atomicAdd(&Tg[mod * 16 + (by >> 3)], tsum);
    }
}

// ---------------- Sinkhorn pass over bf16 q0 (32-row tiles, coalesced) ----------------
// pass 1..5: v-chain -> Sr -> u update -> partial Sc[pass] atomics
// pass 6:    v-chain(v5) -> Sr -> final u -> assign f32 + assign bf16 + colsums
__global__ __launch_bounds__(256) void pass_kernel(const unsigned short* __restrict__ qbg,
                                                   float* __restrict__ u,
                                                   const float* __restrict__ Tg,
                                                   float* __restrict__ Sc,
                                                   float* __restrict__ cs,
                                                   float* __restrict__ doutf,
                                                   unsigned short* __restrict__ abf,
                                                   int pass) {
    __shared__ float vcur[256];
    __shared__ float unl[32];
    __shared__ float wsum[4][256];
    int tile = blockIdx.x, b = blockIdx.y, mod = blockIdx.z;
    int t = threadIdx.x;
    {
        float v = 1.0f;
        for (int j = 1; j < pass; j++) {
            float sc = Sc[((size_t)(mod * 6 + j) * 16 + b) * 256 + t];
            v = v * (1.0f / 256.0f) / (v * sc + EPS);
        }
        vcur[t] = v;
    }
    __syncthreads();

    // ---- phase A: row sums (8 lanes per row, 32 rows) ----
    int r = t >> 3, q = t & 7;
    size_t row = (size_t)b * 1024 + tile * 32 + r;
    const unsigned short* qrow = qbg + ((size_t)mod * M + row) * 256;
    const short8* q8 = (const short8*)(qrow + q * 32);
    const float4* v4 = (const float4*)(vcur + q * 32);
    float sr = 0.f;
    #pragma unroll
    for (int i = 0; i < 4; i++) {
        short8 qv = q8[i];
        float4 va = v4[2 * i], vb = v4[2 * i + 1];
        sr += bf2f((unsigned short)qv[0]) * va.x + bf2f((unsigned short)qv[1]) * va.y
            + bf2f((unsigned short)qv[2]) * va.z + bf2f((unsigned short)qv[3]) * va.w
            + bf2f((unsigned short)qv[4]) * vb.x + bf2f((unsigned short)qv[5]) * vb.y
            + bf2f((unsigned short)qv[6]) * vb.z + bf2f((unsigned short)qv[7]) * vb.w;
    }
    sr += __shfl_xor(sr, 1);
    sr += __shfl_xor(sr, 2);
    sr += __shfl_xor(sr, 4);

    float up = (pass == 1) ? 1.0f / (Tg[mod * 16 + b] + EPS) : u[(size_t)mod * M + row];
    float un;
    if (pass <= 5) un = up * (1.0f / 1024.0f) / (up * sr + EPS);
    else           un = up / (up * sr + EPS);
    if (q == 0) {
        if (pass <= 5) u[(size_t)mod * M + row] = un;
        unl[r] = un;
    }
    __syncthreads();

    // ---- phase B: row-wise coalesced sweep; col partials in registers ----
    int wv = t >> 6, lane = t & 63;
    float c0 = 0.f, c1 = 0.f, c2 = 0.f, c3 = 0.f;
    float4 vv = *(const float4*)(vcur + lane * 4);
    size_t rowbase = (size_t)mod * M + (size_t)b * 1024 + tile * 32;
    if (pass <= 5) {
        #pragma unroll
        for (int rr8 = 0; rr8 < 8; rr8++) {
            int rr = wv * 8 + rr8;
            float unr = unl[rr];
            ushort4 qv = *(const ushort4*)(qbg + (rowbase + rr) * 256 + lane * 4);
            c0 += bf2f(qv.x) * unr;
            c1 += bf2f(qv.y) * unr;
            c2 += bf2f(qv.z) * unr;
            c3 += bf2f(qv.w) * unr;
        }
    } else {
        float* aout = doutf + OUT_ASSIGN + (size_t)mod * PM;
        unsigned short* ab = abf + (size_t)mod * PM;
        #pragma unroll
        for (int rr8 = 0; rr8 < 8; rr8++) {
            int rr = wv * 8 + rr8;
            float unr = unl[rr];
            size_t ro = ((size_t)b * 1024 + tile * 32 + rr) * 256;
            ushort4 qv = *(const ushort4*)(qbg + (rowbase + rr) * 256 + lane * 4);
            float4 a = make_float4(bf2f(qv.x) * unr * vv.x, bf2f(qv.y) * unr * vv.y,
                                   bf2f(qv.z) * unr * vv.z, bf2f(qv.w) * unr * vv.w);
            *(float4*)(aout + ro + lane * 4) = a;
            ushort4 o;
            o.x = f2bf(a.x); o.y = f2bf(a.y); o.z = f2bf(a.z); o.w = f2bf(a.w);
            *(ushort4*)(ab + ro + lane * 4) = o;
            c0 += a.x; c1 += a.y; c2 += a.z; c3 += a.w;
        }
    }
    *(float4*)&wsum[wv][lane * 4] = make_float4(c0, c1, c2, c3);
    __syncthreads();
    {
        float ssum = wsum[0][t] + wsum[1][t] + wsum[2][t] + wsum[3][t];
        float* dst = (pass <= 5) ? &Sc[((size_t)(mod * 6 + pass) * 16 + b) * 256 + t]
                                 : &cs[((size_t)mod * 16 + b) * 256 + t];
        atomicAdd(dst, ssum);
    }
}

// ---------------- sem consistency scalar ----------------
__global__ __launch_bounds__(256) void sem_kernel(const float* __restrict__ cs,
                                                  float* __restrict__ doutf) {
    int t = threadIdx.x;
    float s = 0.f;
    #pragma unroll
    for (int b = 0; b < 16; b++)
        s += cs[b * 256 + t] * cs[4096 + b * 256 + t];
    #pragma unroll
    for (int mk = 1; mk < 64; mk <<= 1) s += __shfl_xor(s, mk);
    __shared__ float red[4];
    if ((t & 63) == 0) red[t >> 6] = s;
    __syncthreads();
    if (t == 0) {
        float tot = red[0] + red[1] + red[2] + red[3];
        float mv = tot / 16777216.0f;           // B*N*N
        mv = fminf(fmaxf(mv, 0.f), 1.f);
        doutf[OUT_SEM] = 1.0f - mv;
    }
}

extern "C" void kernel_launch(void* const* d_in, const int* in_sizes, int n_in,
                              void* d_out, int out_size, void* d_ws, size_t ws_size,
                              hipStream_t stream) {
    const float* f_rgb = (const float*)d_in[0];
    const float* f_sn  = (const float*)d_in[1];
    const float* p_rgb = (const float*)d_in[2];
    const float* p_sn  = (const float*)d_in[3];
    char* ws = (char*)d_ws;
    unsigned short* xn   = (unsigned short*)(ws + OFF_XN);
    unsigned short* abf  = (unsigned short*)(ws + OFF_XN);   // aliases xn (dead after gemm0)
    unsigned short* qb   = (unsigned short*)(ws + OFF_QB);
    unsigned short* pn   = (unsigned short*)(ws + OFF_PN);
    unsigned short* pnt  = (unsigned short*)(ws + OFF_PNT);
    float* u             = (float*)(ws + OFF_U);
    float* Tg            = (float*)(ws + OFF_T);
    float* Sc            = (float*)(ws + OFF_SC);
    float* cs            = (float*)(ws + OFF_CS);
    float* doutf         = (float*)d_out;

    proto_kernel<<<dim3(512), 64, 0, stream>>>(p_rgb, p_sn, pn, pnt, (float*)(ws + ZERO_OFF));
    prep_kernel<<<dim3(4096, 2), 256, 0, stream>>>(f_rgb, f_sn, xn);
    gemm_kernel<0><<<dim3(2, 128, 2), 256, 0, stream>>>(xn, pn, qb, doutf, Tg);
    for (int p = 1; p <= 6; p++)
        pass_kernel<<<dim3(32, 16, 2), 256, 0, stream>>>(qb, u, Tg, Sc, cs, doutf, abf, p);
    gemm_kernel<1><<<dim3(2, 128, 2), 256, 0, stream>>>(abf, pnt, qb, doutf, Tg);
    sem_kernel<<<1, 256, 0, stream>>>(cs, doutf);
}